// Round 1
// baseline (1322.564 us; speedup 1.0000x reference)
//
#include <hip/hip_runtime.h>

typedef _Float16 h2 __attribute__((ext_vector_type(2)));
typedef _Float16 h8 __attribute__((ext_vector_type(8)));

#define TT 2048
#define HH 64
#define NL 8
#define NB 256

union HU { h8 v; h2 p[4]; };

__device__ __forceinline__ float tanh_fast(float v){
    // tanh(x) = 1 - 2/(exp(2x)+1); exp via fast hw path, rcp via v_rcp_f32
    float e = __expf(2.0f * v);
    float r = __builtin_amdgcn_rcpf(e + 1.0f);
    return fmaf(-2.0f, r, 1.0f);
}

__global__ void __launch_bounds__(512) rnn_kernel(
    const float* __restrict__ x,        // [B,T,64]
    const float* __restrict__ h_state,  // [8,B,64]
    const float* __restrict__ W_ih0,    // [64,64]
    const float* __restrict__ W_ih,     // [7,64,64]
    const float* __restrict__ W_hh,     // [8,64,64]
    const float* __restrict__ b_ih,     // [8,64]
    const float* __restrict__ b_hh,     // [8,64]
    const float* __restrict__ W_out,    // [1,64]
    const float* __restrict__ b_out,    // [1]
    float* __restrict__ out)            // y[256*2048] ++ h_final[8*256*64]
{
    __shared__ __attribute__((aligned(16))) _Float16 lbuf[NL+1][2][HH];
    const int tid  = threadIdx.x;
    const int wv   = tid >> 6;     // wave id == layer id
    const int lane = tid & 63;
    const size_t b = blockIdx.x;

    // ---- load this layer's weights into registers (packed f16 pairs, row = lane)
    h2 wih[32], whh[32], wout2[32];
    const float2* wi = (const float2*)(wv == 0 ? W_ih0 : (W_ih + (size_t)(wv-1)*HH*HH));
    const float2* wh = (const float2*)(W_hh + (size_t)wv*HH*HH);
    #pragma unroll
    for (int i = 0; i < 32; ++i){
        float2 a = wi[lane*32 + i];
        float2 c = wh[lane*32 + i];
        wih[i] = h2{(_Float16)a.x, (_Float16)a.y};
        whh[i] = h2{(_Float16)c.x, (_Float16)c.y};
    }
    float bsum = b_ih[wv*HH + lane] + b_hh[wv*HH + lane];
    float bout = 0.f;
    if (wv == 7){
        const float2* wo = (const float2*)W_out;
        #pragma unroll
        for (int i = 0; i < 32; ++i){
            float2 a = wo[i];
            wout2[i] = h2{(_Float16)a.x, (_Float16)a.y};
        }
        bout = b_out[0];
    }

    // ---- zero LDS, then place initial state
    for (int i = tid; i < (NL+1)*2*HH; i += 512) ((_Float16*)lbuf)[i] = (_Float16)0.f;
    __syncthreads();
    // wave l first reads its own h at n=l from phase (l-1)&1 == (l+1)&1
    lbuf[wv+1][(wv+1)&1][lane] = (_Float16)h_state[((size_t)wv*NB + b)*HH + lane];
    float xa[4] = {0.f, 0.f, 0.f, 0.f};   // static-indexed x prefetch ring (wave 0)
    if (wv == 0){
        lbuf[0][1][lane] = (_Float16)x[(b*TT + 0)*HH + lane];   // x[t=0], read at n=0
        xa[1] = x[(b*TT + 1)*HH + lane];
        xa[2] = x[(b*TT + 2)*HH + lane];
        xa[3] = x[(b*TT + 3)*HH + lane];
        xa[0] = x[(b*TT + 4)*HH + lane];
    }
    __syncthreads();

    float* yout = out;                    // [B*T]
    float* hout = out + (size_t)NB*TT;    // [8,B,64]

    #pragma unroll 4
    for (int n = 0; n < TT + NL; ++n){
        const int t = n - wv;
        const bool active = (t >= 0) & (t < TT);
        const int pr = (n + 1) & 1;       // phase written last iteration
        const int pw = n & 1;             // phase written this iteration
        const h8* ib = (const h8*)(&lbuf[wv][pr][0]);       // inp from layer-1 (or x)
        const h8* hb = (const h8*)(&lbuf[wv+1][pr][0]);     // own h (t-1)

        // 8 independent accumulator chains (depth 8 each) instead of one
        // 64-deep serial chain: the recurrence is latency-bound, not
        // issue-bound (VALUBusy 44.6% at 2 waves/SIMD).
        float a0 = bsum, a1 = 0.f, a2 = 0.f, a3 = 0.f;
        float a4 = 0.f,  a5 = 0.f, a6 = 0.f, a7 = 0.f;
        h8 hvs[8];
        #pragma unroll
        for (int u = 0; u < 8; ++u){
            HU iu, hu;
            iu.v = ib[u];                 // ds_read_b128 broadcast
            hu.v = hb[u];
            hvs[u] = hu.v;
            a0 = __builtin_amdgcn_fdot2(wih[u*4+0], iu.p[0], a0, false);
            a1 = __builtin_amdgcn_fdot2(wih[u*4+1], iu.p[1], a1, false);
            a2 = __builtin_amdgcn_fdot2(wih[u*4+2], iu.p[2], a2, false);
            a3 = __builtin_amdgcn_fdot2(wih[u*4+3], iu.p[3], a3, false);
            a4 = __builtin_amdgcn_fdot2(whh[u*4+0], hu.p[0], a4, false);
            a5 = __builtin_amdgcn_fdot2(whh[u*4+1], hu.p[1], a5, false);
            a6 = __builtin_amdgcn_fdot2(whh[u*4+2], hu.p[2], a6, false);
            a7 = __builtin_amdgcn_fdot2(whh[u*4+3], hu.p[3], a7, false);
        }
        float acc = ((a0 + a1) + (a2 + a3)) + ((a4 + a5) + (a6 + a7));
        float hn = tanh_fast(acc);

        if (wv == 7){
            // y[t-1] from the h7[t-1] we just broadcast-read (off critical path)
            float y0 = bout, y1 = 0.f, y2 = 0.f, y3 = 0.f;
            #pragma unroll
            for (int u = 0; u < 8; ++u){
                HU hu; hu.v = hvs[u];
                y0 = __builtin_amdgcn_fdot2(wout2[u*4+0], hu.p[0], y0, false);
                y1 = __builtin_amdgcn_fdot2(wout2[u*4+1], hu.p[1], y1, false);
                y2 = __builtin_amdgcn_fdot2(wout2[u*4+2], hu.p[2], y2, false);
                y3 = __builtin_amdgcn_fdot2(wout2[u*4+3], hu.p[3], y3, false);
            }
            float ysum = (y0 + y1) + (y2 + y3);
            int ty = n - 8;
            if (ty >= 0 && lane == 0) yout[b*TT + ty] = ysum;
        }

        if (active){
            lbuf[wv+1][pw][lane] = (_Float16)hn;            // handoff to next layer / self
            if (t == TT-1) hout[((size_t)wv*NB + b)*HH + lane] = hn;
        }
        if (wv == 0){
            int tw = n + 1;                                  // stage x[t=n+1] for next iter
            if (tw < TT) lbuf[0][pw][lane] = (_Float16)xa[tw & 3];
            int tl = n + 5;                                  // refill ring 4 iters ahead
            if (tl < TT) xa[tl & 3] = x[(b*TT + tl)*HH + lane];
        }
        __syncthreads();
    }
}

extern "C" void kernel_launch(void* const* d_in, const int* in_sizes, int n_in,
                              void* d_out, int out_size, void* d_ws, size_t ws_size,
                              hipStream_t stream) {
    (void)in_sizes; (void)n_in; (void)d_ws; (void)ws_size; (void)out_size;
    const float* x       = (const float*)d_in[0];
    const float* h_state = (const float*)d_in[1];
    const float* W_ih0   = (const float*)d_in[2];
    const float* W_ih    = (const float*)d_in[3];
    const float* W_hh    = (const float*)d_in[4];
    const float* b_ih    = (const float*)d_in[5];
    const float* b_hh    = (const float*)d_in[6];
    const float* W_out   = (const float*)d_in[7];
    const float* b_out   = (const float*)d_in[8];
    float* out = (float*)d_out;

    rnn_kernel<<<dim3(NB), dim3(512), 0, stream>>>(
        x, h_state, W_ih0, W_ih, W_hh, b_ih, b_hh, W_out, b_out, out);
}

// Round 3
// 1217.300 us; speedup vs baseline: 1.0865x; 1.0865x over previous
//
#include <hip/hip_runtime.h>

typedef _Float16 h2 __attribute__((ext_vector_type(2)));
typedef _Float16 h8 __attribute__((ext_vector_type(8)));

#define TT 2048
#define HH 64
#define NL 8
#define NB 256

union HU { h8 v; h2 p[4]; };

__device__ __forceinline__ float tanh_fast(float v){
    // tanh(x) = 1 - 2/(exp(2x)+1); exp via fast hw path, rcp via v_rcp_f32
    float e = __expf(2.0f * v);
    float r = __builtin_amdgcn_rcpf(e + 1.0f);
    return fmaf(-2.0f, r, 1.0f);
}

// Barrier that drains ONLY lgkmcnt (LDS visibility), leaving vmem
// (wave-0 x prefetch loads, wave-7 y stores) in flight across the
// barrier. __syncthreads() would emit s_waitcnt vmcnt(0) and expose
// HBM latency every iteration, defeating the prefetch ring.
__device__ __forceinline__ void barrier_lgkm_only(){
    asm volatile("" ::: "memory");                 // ds_write stays above
    __builtin_amdgcn_s_waitcnt(0xc07f);            // lgkmcnt(0), vmcnt/expcnt = max
    __builtin_amdgcn_s_barrier();
    asm volatile("" ::: "memory");                 // next-iter ds_reads stay below
}

__global__ void __launch_bounds__(512) rnn_kernel(
    const float* __restrict__ x,        // [B,T,64]
    const float* __restrict__ h_state,  // [8,B,64]
    const float* __restrict__ W_ih0,    // [64,64]
    const float* __restrict__ W_ih,     // [7,64,64]
    const float* __restrict__ W_hh,     // [8,64,64]
    const float* __restrict__ b_ih,     // [8,64]
    const float* __restrict__ b_hh,     // [8,64]
    const float* __restrict__ W_out,    // [1,64]
    const float* __restrict__ b_out,    // [1]
    float* __restrict__ out)            // y[256*2048] ++ h_final[8*256*64]
{
    __shared__ __attribute__((aligned(16))) _Float16 lbuf[NL+1][2][HH];
    const int tid  = threadIdx.x;
    const int wv   = tid >> 6;     // wave id == layer id
    const int lane = tid & 63;
    const size_t b = blockIdx.x;

    // ---- load this layer's weights into registers (packed f16 pairs, row = lane)
    h2 wih[32], whh[32], wout2[32];
    const float2* wi = (const float2*)(wv == 0 ? W_ih0 : (W_ih + (size_t)(wv-1)*HH*HH));
    const float2* wh = (const float2*)(W_hh + (size_t)wv*HH*HH);
    #pragma unroll
    for (int i = 0; i < 32; ++i){
        float2 a = wi[lane*32 + i];
        float2 c = wh[lane*32 + i];
        wih[i] = h2{(_Float16)a.x, (_Float16)a.y};
        whh[i] = h2{(_Float16)c.x, (_Float16)c.y};
    }
    float bsum = b_ih[wv*HH + lane] + b_hh[wv*HH + lane];
    float bout = 0.f;
    if (wv == 7){
        const float2* wo = (const float2*)W_out;
        #pragma unroll
        for (int i = 0; i < 32; ++i){
            float2 a = wo[i];
            wout2[i] = h2{(_Float16)a.x, (_Float16)a.y};
        }
        bout = b_out[0];
    }

    // ---- zero LDS, then place initial state
    for (int i = tid; i < (NL+1)*2*HH; i += 512) ((_Float16*)lbuf)[i] = (_Float16)0.f;
    __syncthreads();
    // wave l first reads its own h at n=l from phase (l-1)&1 == (l+1)&1
    lbuf[wv+1][(wv+1)&1][lane] = (_Float16)h_state[((size_t)wv*NB + b)*HH + lane];
    float xa[4] = {0.f, 0.f, 0.f, 0.f};   // static-indexed x prefetch ring (wave 0)
    if (wv == 0){
        lbuf[0][1][lane] = (_Float16)x[(b*TT + 0)*HH + lane];   // x[t=0], read at n=0
        xa[1] = x[(b*TT + 1)*HH + lane];
        xa[2] = x[(b*TT + 2)*HH + lane];
        xa[3] = x[(b*TT + 3)*HH + lane];
        xa[0] = x[(b*TT + 4)*HH + lane];
    }
    __syncthreads();

    float* yout = out;                    // [B*T]
    float* hout = out + (size_t)NB*TT;    // [8,B,64]

    #pragma unroll 4
    for (int n = 0; n < TT + NL; ++n){
        const int t = n - wv;
        const bool active = (t >= 0) & (t < TT);
        const int pr = (n + 1) & 1;       // phase written last iteration
        const int pw = n & 1;             // phase written this iteration
        const h8* ib = (const h8*)(&lbuf[wv][pr][0]);       // inp from layer-1 (or x)
        const h8* hb = (const h8*)(&lbuf[wv+1][pr][0]);     // own h (t-1)

        float acc = bsum;
        h8 hvs[8];
        #pragma unroll
        for (int u = 0; u < 8; ++u){
            HU iu, hu;
            iu.v = ib[u];                 // ds_read_b128 broadcast
            hu.v = hb[u];
            hvs[u] = hu.v;
            #pragma unroll
            for (int k = 0; k < 4; ++k){
                acc = __builtin_amdgcn_fdot2(wih[u*4 + k], iu.p[k], acc, false);
                acc = __builtin_amdgcn_fdot2(whh[u*4 + k], hu.p[k], acc, false);
            }
        }
        float hn = tanh_fast(acc);

        if (wv == 7){
            // y[t-1] from the h7[t-1] we just broadcast-read (off critical path)
            float ysum = bout;
            #pragma unroll
            for (int u = 0; u < 8; ++u){
                HU hu; hu.v = hvs[u];
                #pragma unroll
                for (int k = 0; k < 4; ++k)
                    ysum = __builtin_amdgcn_fdot2(wout2[u*4 + k], hu.p[k], ysum, false);
            }
            int ty = n - 8;
            if (ty >= 0 && lane == 0) yout[b*TT + ty] = ysum;
        }

        if (active){
            lbuf[wv+1][pw][lane] = (_Float16)hn;            // handoff to next layer / self
            if (t == TT-1) hout[((size_t)wv*NB + b)*HH + lane] = hn;
        }
        if (wv == 0){
            int tw = n + 1;                                  // stage x[t=n+1] for next iter
            if (tw < TT) lbuf[0][pw][lane] = (_Float16)xa[tw & 3];
            int tl = n + 5;                                  // refill ring 4 iters ahead
            if (tl < TT) xa[tl & 3] = x[(b*TT + tl)*HH + lane];
        }
        barrier_lgkm_only();
    }
}

extern "C" void kernel_launch(void* const* d_in, const int* in_sizes, int n_in,
                              void* d_out, int out_size, void* d_ws, size_t ws_size,
                              hipStream_t stream) {
    (void)in_sizes; (void)n_in; (void)d_ws; (void)ws_size; (void)out_size;
    const float* x       = (const float*)d_in[0];
    const float* h_state = (const float*)d_in[1];
    const float* W_ih0   = (const float*)d_in[2];
    const float* W_ih    = (const float*)d_in[3];
    const float* W_hh    = (const float*)d_in[4];
    const float* b_ih    = (const float*)d_in[5];
    const float* b_hh    = (const float*)d_in[6];
    const float* W_out   = (const float*)d_in[7];
    const float* b_out   = (const float*)d_in[8];
    float* out = (float*)d_out;

    rnn_kernel<<<dim3(NB), dim3(512), 0, stream>>>(
        x, h_state, W_ih0, W_ih, W_hh, b_ih, b_hh, W_out, b_out, out);
}